// Round 9
// baseline (180.130 us; speedup 1.0000x reference)
//
#include <hip/hip_runtime.h>
#include <hip/hip_fp16.h>

// Problem: B=2, H=8, L=2048, D=64.
// out0 = masked(p + p^T) @ v   (B,H,L,D)
// out1 = p + p^T               (B,H,L,L)
// p[b,h,qi,ki] += exp(-(q_sorted_r - k_sorted_r)^2)/D for rank-matched sorted
// q/k along L per (b,h,d). Each attn row receives exactly 64 direct + 64
// transpose entries (one per d) -> collision-free 4B slot per entry in the
// first 512B of each row's dense output region (u16 col | fp16 weight).
//
// 2-kernel pipeline (no workspace):
//   sort_emit: strided q/k loads (L2-shared: all 64 d-blocks of a bh are
//              co-resident on one XCD; working set 2.1 MB < 4 MB L2),
//              2x bitonic sort, rank-match, scatter entries.
//   row:       inline mask bit-pack (ballots), compact, gather-matvec,
//              densify + NT dense-row stores.

#define LSEQ 2048
#define DDIM 64
#define NBH  16
#define SNTHR 512   // sort threads/block
#define SEPT  4     // sort elements/thread

typedef float    f32x4 __attribute__((ext_vector_type(4)));
typedef unsigned u32x2 __attribute__((ext_vector_type(2)));

#define LGKM0() asm volatile("s_waitcnt lgkmcnt(0)" ::: "memory")

__device__ __forceinline__ unsigned long long pack_kv(float f, unsigned idx) {
  unsigned u = __float_as_uint(f);
  u = (u & 0x80000000u) ? ~u : (u | 0x80000000u);   // sortable-ascending
  return ((unsigned long long)u << 32) | idx;
}

__device__ __forceinline__ float unpack_val(unsigned long long p) {
  unsigned us = (unsigned)(p >> 32);
  unsigned u = (us & 0x80000000u) ? (us & 0x7fffffffu) : ~us;
  return __uint_as_float(u);
}

#define CSWP(a, x, y, up) \
  { if ((a[x] > a[y]) == (up)) { auto _t = a[x]; a[x] = a[y]; a[y] = _t; } }

// full bitonic sort of 4 contiguous elems (base index 4t); u4 = dir for kk=4
__device__ __forceinline__ void sort4(unsigned long long* a, bool u4) {
  CSWP(a,0,1,true); CSWP(a,2,3,false);          // kk=2
  CSWP(a,0,2,u4);  CSWP(a,1,3,u4);              // kk=4, j=2
  CSWP(a,0,1,u4);  CSWP(a,2,3,u4);              // kk=4, j=1
}

// bitonic merge j=2,1 over 4 contiguous elems, uniform direction
__device__ __forceinline__ void merge4(unsigned long long* a, bool up) {
  CSWP(a,0,2,up); CSWP(a,1,3,up);
  CSWP(a,0,1,up); CSWP(a,2,3,up);
}

__device__ __forceinline__ unsigned long long bmin(unsigned long long a, unsigned long long b) {
  return a < b ? a : b;
}
__device__ __forceinline__ unsigned long long bmax(unsigned long long a, unsigned long long b) {
  return a > b ? a : b;
}

// One block (512 thr) per (b,h,d): sort q-slice & k-slice (2048 each),
// rank-match, scatter entries. Thread t owns elements [4t, 4t+4).
// Stages j<=2: in-register merge4. Stages j=4..128: __shfl_xor (same wave).
// Stages j>=256: cross-wave via one 16KB LDS buffer, two passes (rq, rk).
__global__ __launch_bounds__(SNTHR, 4) void sort_emit_kernel(
    const float* __restrict__ q, const float* __restrict__ k,
    float* __restrict__ attn) {
  __shared__ unsigned long long sx[SEPT][SNTHR];   // 16 KB
  const int bid = blockIdx.x;
  const int lb  = (bid & 7) * (NBH * DDIM / 8) + (bid >> 3);  // XCD chunking
  const int bh = lb >> 6, d = lb & 63;
  const int t = threadIdx.x;

  // strided direct loads: element l of slice (bh, :, d) at q[bh*L*D + l*D + d].
  // All 64 d-blocks of this bh run on the same XCD -> lines L2-shared.
  unsigned long long rq[SEPT], rk[SEPT];
  {
    const size_t base = (size_t)bh * LSEQ * DDIM + d;
    #pragma unroll
    for (int p = 0; p < SEPT; ++p) {
      int l = 4*t + p;
      rq[p] = pack_kv(q[base + (size_t)l * DDIM], l);
      rk[p] = pack_kv(k[base + (size_t)l * DDIM], l);
    }
  }

  sort4(rq, (t & 1) == 0);
  sort4(rk, (t & 1) == 0);

  for (int kk = 8; kk <= LSEQ; kk <<= 1) {
    const bool up = (((4 * t) & kk) == 0);
    // LDS stages: j >= 256 (partner thread in another wave); two passes
    for (int j = kk >> 1; j >= 256; j >>= 1) {
      const int m = j >> 2;                 // 64,128,256
      const int pt = t ^ m;
      const bool ks = (((t & m) == 0) == up);
      __syncthreads();
      #pragma unroll
      for (int p = 0; p < SEPT; ++p) sx[p][t] = rq[p];
      __syncthreads();
      #pragma unroll
      for (int p = 0; p < SEPT; ++p) {
        unsigned long long aq = sx[p][pt];
        rq[p] = ks ? bmin(rq[p], aq) : bmax(rq[p], aq);
      }
      __syncthreads();
      #pragma unroll
      for (int p = 0; p < SEPT; ++p) sx[p][t] = rk[p];
      __syncthreads();
      #pragma unroll
      for (int p = 0; p < SEPT; ++p) {
        unsigned long long ak = sx[p][pt];
        rk[p] = ks ? bmin(rk[p], ak) : bmax(rk[p], ak);
      }
    }
    // shfl stages: 4 <= j <= 128 (partner lane = t ^ (j/4), same wave)
    const int jstart = (kk >> 1) < 128 ? (kk >> 1) : 128;
    for (int j = jstart; j >= 4; j >>= 1) {
      const int m = j >> 2;                 // 1..32
      const bool ks = (((t & m) == 0) == up);
      #pragma unroll
      for (int p = 0; p < SEPT; ++p) {
        unsigned long long aq = __shfl_xor(rq[p], m);
        unsigned long long ak = __shfl_xor(rk[p], m);
        rq[p] = ks ? bmin(rq[p], aq) : bmax(rq[p], aq);
        rk[p] = ks ? bmin(rk[p], ak) : bmax(rk[p], ak);
      }
    }
    merge4(rq, up);
    merge4(rk, up);
  }

  // emit from registers; rank r = 4t+p, final order ascending.
  // entry = u16 col | fp16 weight  (4B; w <= 1/64, fp16 rel err 2^-11)
  float* abh = attn + (size_t)bh * LSEQ * LSEQ;
  #pragma unroll
  for (int p = 0; p < SEPT; ++p) {
    unsigned qi = (unsigned)(rq[p] & 0xffffffffu);
    unsigned ki = (unsigned)(rk[p] & 0xffffffffu);
    float qv = unpack_val(rq[p]);
    float kv = unpack_val(rk[p]);
    float diff = qv - kv;
    float w = expf(-diff * diff) * (1.0f / (float)DDIM);
    unsigned hw = (unsigned)__half_as_ushort(__float2half(w));
    ((unsigned*)(abh + (size_t)qi * LSEQ))[d]      = ki | (hw << 16);  // slot d
    ((unsigned*)(abh + (size_t)ki * LSEQ))[64 + d] = qi | (hw << 16);  // slot 64+d
  }
}

__device__ __forceinline__ float half_bits_to_f32(unsigned bits) {
  return __half2float(__ushort_as_half((unsigned short)bits));
}

// One WAVE per attn row (128-thr blocks = 2 independent waves, NO
// __syncthreads -- all LDS state is per-wave, ordered by wave-local lgkmcnt).
// Phase order: entry load + inline mask bit-pack -> compaction -> matvec
// (loads only) -> out store -> densify + NT dense-row stores LAST (so no
// v-load ever waits behind an outstanding store in the vmcnt FIFO).
__global__ __launch_bounds__(128) void row_kernel(
    float* __restrict__ attn, const float* __restrict__ v,
    const int* __restrict__ mask, float* __restrict__ out) {
  __shared__ float rowbuf[2][1024];
  __shared__ unsigned cent[2][136];              // compacted active entries
  __shared__ unsigned long long mb[2][32];
  const int wv = threadIdx.x >> 6, lane = threadIdx.x & 63;
  const int bid = blockIdx.x;
  const int lb = (bid & 7) * ((NBH * LSEQ / 2) / 8) + (bid >> 3);  // XCD chunking
  const int R = lb * 2 + wv;
  const int bh = R >> 11, r = R & (LSEQ - 1);
  float* arow = attn + (size_t)R * LSEQ;

  // phase 1: entry list (first 512B of this row's dense region, L2-dirty
  // from sort on this XCD) + inline mask-row bit-pack via ballots.
  u32x2 ep = __builtin_nontemporal_load(((const u32x2*)arow) + lane);
  {
    const int* mrow = mask + (size_t)r * LSEQ;
    #pragma unroll
    for (int w = 0; w < 32; ++w) {
      unsigned long long b = __ballot(mrow[w * 64 + lane] != 0);
      if (lane == 0) mb[wv][w] = b;
    }
  }
  LGKM0();

  // phase 2: active tests + ballot compaction (lane holds entries 2l, 2l+1)
  const unsigned cA = ep.x & 0xFFFFu, cB = ep.y & 0xFFFFu;
  bool aA = !((mb[wv][cA >> 6] >> (cA & 63)) & 1ull);
  bool aB = !((mb[wv][cB >> 6] >> (cB & 63)) & 1ull);
  unsigned long long m0 = __ballot(aA), m1 = __ballot(aB);
  int n0 = __popcll(m0);
  int n  = n0 + __popcll(m1);
  if (aA) cent[wv][__popcll(m0 & ((1ull << lane) - 1ull))] = ep.x;
  if (aB) cent[wv][n0 + __popcll(m1 & ((1ull << lane) - 1ull))] = ep.y;
  int npad = (n + 7) & ~7;
  if (lane < npad - n) cent[wv][n + lane] = 0u;   // col 0, w = 0
  LGKM0();

  // phase 3: matvec over active entries only (pure loads, 8 accumulators)
  const float* vb = v + (size_t)bh * LSEQ * DDIM;
  float acc[8];
  #pragma unroll
  for (int u = 0; u < 8; ++u) acc[u] = 0.0f;
  for (int e = 0; e < npad; e += 8) {
    #pragma unroll
    for (int u = 0; u < 8; ++u) {
      unsigned en = cent[wv][e + u];
      acc[u] += half_bits_to_f32(en >> 16) * vb[(size_t)(en & 0xFFFFu) * DDIM + lane];
    }
  }
  float s = ((acc[0] + acc[1]) + (acc[2] + acc[3])) +
            ((acc[4] + acc[5]) + (acc[6] + acc[7]));
  out[(size_t)R * DDIM + lane] = s;

  // phase 4: densify + dense-row NT stores (LAST; nothing waits on them)
  const float wA = half_bits_to_f32(ep.x >> 16);
  const float wB = half_bits_to_f32(ep.y >> 16);
  #pragma unroll
  for (int h = 0; h < 2; ++h) {
    f32x4 z = {0.0f, 0.0f, 0.0f, 0.0f};
    #pragma unroll
    for (int i = 0; i < 4; ++i) ((f32x4*)rowbuf[wv])[i * 64 + lane] = z;
    LGKM0();
    if ((int)(cA >> 10) == h) atomicAdd(&rowbuf[wv][cA & 1023], wA);
    if ((int)(cB >> 10) == h) atomicAdd(&rowbuf[wv][cB & 1023], wB);
    LGKM0();
    #pragma unroll
    for (int i = 0; i < 4; ++i) {
      f32x4 val = ((const f32x4*)rowbuf[wv])[i * 64 + lane];
      __builtin_nontemporal_store(val, ((f32x4*)(arow + (h << 10))) + i * 64 + lane);
    }
    LGKM0();   // rowbuf reads drained before next-half zeroing
  }
}

extern "C" void kernel_launch(void* const* d_in, const int* in_sizes, int n_in,
                              void* d_out, int out_size, void* d_ws, size_t ws_size,
                              hipStream_t stream) {
  const float* q = (const float*)d_in[0];
  const float* k = (const float*)d_in[1];
  const float* v = (const float*)d_in[2];
  const int* mask = (const int*)d_in[3];
  float* out = (float*)d_out;
  float* attn = out + (size_t)NBH * LSEQ * DDIM;

  sort_emit_kernel<<<NBH * DDIM, SNTHR, 0, stream>>>(q, k, attn);
  row_kernel<<<(NBH * LSEQ) / 2, 128, 0, stream>>>(attn, v, mask, out);
}